// Round 7
// baseline (226.169 us; speedup 1.0000x reference)
//
#include <hip/hip_runtime.h>

typedef __attribute__((ext_vector_type(8))) short short8;
typedef __attribute__((ext_vector_type(4))) float float4v;

__device__ __forceinline__ unsigned short f2bf(float f) {
    unsigned u = __float_as_uint(f);
    u = (u + 0x7FFFu + ((u >> 16) & 1u)) >> 16;
    return (unsigned short)u;
}

#define XSET 520   // 512 data + 8 pad ushorts per (g,ks) fragment set
#define CROW 68    // 64 px + 4 pad floats per staged C row
// LDS map:
//   [0, 33312)      X frags (never aliased)
//   [33312, 50720)  Z frags (12480 B) / C staging (17408 B), barrier-separated
#define X_BYTES 33312
#define SMEM_BYTES 50720   // 3 blocks/CU

// ---------------------------------------------------------------------------
// Prepack: W1 [256x64], W2 [96x256] ([cin,cout]) -> bf16 MFMA A-frag order.
// ---------------------------------------------------------------------------
__global__ void prepack(const float* __restrict__ W1_0, const float* __restrict__ W2_0,
                        const float* __restrict__ W1_1, const float* __restrict__ W2_1,
                        const float* __restrict__ W1_2, const float* __restrict__ W2_2,
                        unsigned short* __restrict__ ws) {
    int e = blockIdx.x * 256 + threadIdx.x;
    if (e >= 3 * 40960) return;
    int l = e / 40960, r = e % 40960;
    const float* W1 = (l == 0) ? W1_0 : (l == 1) ? W1_1 : W1_2;
    const float* W2 = (l == 0) ? W2_0 : (l == 1) ? W2_1 : W2_2;
    unsigned short* base = ws + l * 40960;
    if (r < 16384) {
        int j = r & 7, lane = (r >> 3) & 63, fs = r >> 9;
        int mt = fs >> 3, ks = fs & 7;
        int k = ks * 32 + (lane >> 4) * 8 + j;
        int m = mt * 16 + (lane & 15);
        base[r] = f2bf(W1[k * 64 + m]);
    } else {
        int r2 = r - 16384;
        int j = r2 & 7, lane = (r2 >> 3) & 63, fs = r2 >> 9;
        int mt = fs / 3, ks = fs - mt * 3;
        int k = ks * 32 + (lane >> 4) * 8 + j;
        int m = mt * 16 + (lane & 15);
        base[16384 + r2] = f2bf(W2[k * 256 + m]);
    }
}

// ---- helpers ---------------------------------------------------------------

// By-value single-vector scatter; I is compile-time -> no array, no pointer
// decay, nothing for the allocator to demote (v8/v9 spilled exactly the
// float4v v[16] prefetch array: dFETCH == 256 B/thread).
template<int I>
__device__ __forceinline__ void scat1(float4v vv, unsigned short* xs,
                                      int g, int n0, int ch_lo) {
    const int ch = I * 16 + ch_lo;
    const int ks = ch >> 5, qq = (ch >> 3) & 3, j = ch & 7;
    // +g*8 ushort (16 B) skew breaks the mod-32-bank degeneracy.
    unsigned short* base = xs + (g * 8 + ks) * XSET + g * 8 + j;
    base[(qq * 16 + n0 + 0) * 8] = f2bf(vv[0]);
    base[(qq * 16 + n0 + 1) * 8] = f2bf(vv[1]);
    base[(qq * 16 + n0 + 2) * 8] = f2bf(vv[2]);
    base[(qq * 16 + n0 + 3) * 8] = f2bf(vv[3]);
}

__device__ __forceinline__ void fragread(short8 xf[8], const unsigned short* xs,
                                         int w, int lane) {
#pragma unroll
    for (int ks = 0; ks < 8; ++ks)
        xf[ks] = *(const short8*)(xs + (w * 8 + ks) * XSET + w * 8 + lane * 8);
}

__device__ __forceinline__ void mfma1(float4v acc1[4], const short8 xf[8],
                                      const short8* __restrict__ A1f,
                                      const float* __restrict__ b1, int lane, int q) {
#pragma unroll
    for (int mt = 0; mt < 4; ++mt)
        acc1[mt] = *(const float4v*)(b1 + mt * 16 + q * 4);
#pragma unroll
    for (int ks = 0; ks < 8; ++ks)
#pragma unroll
        for (int mt = 0; mt < 4; ++mt)
            acc1[mt] = __builtin_amdgcn_mfma_f32_16x16x32_bf16(
                A1f[(mt * 8 + ks) * 64 + lane], xf[ks], acc1[mt], 0, 0, 0);
}

__device__ __forceinline__ void zwrite(const float4v acc1[4], unsigned short* zs,
                                       int w, int q, int n) {
    unsigned short* zg = zs + w * 3 * XSET;
#pragma unroll
    for (int mt = 0; mt < 4; ++mt) {
        const int kb = mt * 16 + q * 4;
        unsigned long long pk =
              (unsigned long long)f2bf(acc1[mt][0])
            | ((unsigned long long)f2bf(acc1[mt][1]) << 16)
            | ((unsigned long long)f2bf(acc1[mt][2]) << 32)
            | ((unsigned long long)f2bf(acc1[mt][3]) << 48);
        *(unsigned long long*)(zg + (kb >> 5) * XSET +
            (((kb >> 3) & 3) * 16 + n) * 8 + (kb & 7)) = pk;
        if (mt >= 2) {
            const int kr = kb + 32;        // relu copy at k = 64 + (ch-32)
            unsigned long long pr =
                  (unsigned long long)f2bf(fmaxf(acc1[mt][0], 0.f))
                | ((unsigned long long)f2bf(fmaxf(acc1[mt][1], 0.f)) << 16)
                | ((unsigned long long)f2bf(fmaxf(acc1[mt][2], 0.f)) << 32)
                | ((unsigned long long)f2bf(fmaxf(acc1[mt][3], 0.f)) << 48);
            *(unsigned long long*)(zg + (kr >> 5) * XSET +
                (((kr >> 3) & 3) * 16 + n) * 8 + (kr & 7)) = pr;
        }
    }
}

__device__ __forceinline__ void mfma2(float4v acc2[4][4], const unsigned short* zs,
                                      const short8* __restrict__ A2f,
                                      const float* __restrict__ b2,
                                      int lane, int w, int q) {
#pragma unroll
    for (int mm = 0; mm < 4; ++mm) {
        float4v bb = *(const float4v*)(b2 + (w * 4 + mm) * 16 + q * 4);
#pragma unroll
        for (int g = 0; g < 4; ++g) acc2[mm][g] = bb;
    }
#pragma unroll
    for (int g = 0; g < 4; ++g) {
        short8 zf[3];
#pragma unroll
        for (int ks = 0; ks < 3; ++ks)
            zf[ks] = *(const short8*)(zs + (g * 3 + ks) * XSET + lane * 8);
#pragma unroll
        for (int ks = 0; ks < 3; ++ks)
#pragma unroll
            for (int mm = 0; mm < 4; ++mm)
                acc2[mm][g] = __builtin_amdgcn_mfma_f32_16x16x32_bf16(
                    A2f[((w * 4 + mm) * 3 + ks) * 64 + lane], zf[ks], acc2[mm][g], 0, 0, 0);
    }
}

// C staging: 16-row wave-private slots, 4 passes (one mm each). DS ops of one
// wave execute in order -> no barrier inside.
template<int HW>
__device__ __forceinline__ void cstore(const float4v acc2[4][4], float* cb,
                                       float* __restrict__ o, int px0,
                                       int lane, int w, int q, int n) {
    float* cww = cb + w * 16 * CROW;
    const int chs = lane >> 4, ppx = lane & 15;
#pragma unroll
    for (int mm = 0; mm < 4; ++mm) {
#pragma unroll
        for (int g = 0; g < 4; ++g)
#pragma unroll
            for (int r = 0; r < 4; ++r)
                cww[(q * 4 + r) * CROW + g * 16 + n] = acc2[mm][g][r];
        float* op = o + (size_t)(w * 64 + mm * 16 + chs) * HW + px0 + 4 * ppx;
#pragma unroll
        for (int i = 0; i < 4; ++i) {
            float4v vv = *(const float4v*)(cww + (i * 4 + chs) * CROW + 4 * ppx);
            *(float4v*)(op + (size_t)(i * 4) * HW) = vv;
        }
    }
}

#define LDALL(OFF)                                                        \
    vv0  = *(const float4v*)(xp + (OFF) + (size_t)( 0 * 16) * HW);        \
    vv1  = *(const float4v*)(xp + (OFF) + (size_t)( 1 * 16) * HW);        \
    vv2  = *(const float4v*)(xp + (OFF) + (size_t)( 2 * 16) * HW);        \
    vv3  = *(const float4v*)(xp + (OFF) + (size_t)( 3 * 16) * HW);        \
    vv4  = *(const float4v*)(xp + (OFF) + (size_t)( 4 * 16) * HW);        \
    vv5  = *(const float4v*)(xp + (OFF) + (size_t)( 5 * 16) * HW);        \
    vv6  = *(const float4v*)(xp + (OFF) + (size_t)( 6 * 16) * HW);        \
    vv7  = *(const float4v*)(xp + (OFF) + (size_t)( 7 * 16) * HW);        \
    vv8  = *(const float4v*)(xp + (OFF) + (size_t)( 8 * 16) * HW);        \
    vv9  = *(const float4v*)(xp + (OFF) + (size_t)( 9 * 16) * HW);        \
    vv10 = *(const float4v*)(xp + (OFF) + (size_t)(10 * 16) * HW);        \
    vv11 = *(const float4v*)(xp + (OFF) + (size_t)(11 * 16) * HW);        \
    vv12 = *(const float4v*)(xp + (OFF) + (size_t)(12 * 16) * HW);        \
    vv13 = *(const float4v*)(xp + (OFF) + (size_t)(13 * 16) * HW);        \
    vv14 = *(const float4v*)(xp + (OFF) + (size_t)(14 * 16) * HW);        \
    vv15 = *(const float4v*)(xp + (OFF) + (size_t)(15 * 16) * HW);

#define SCALL()                                                           \
    scat1< 0>(vv0,  xs, g, n0, ch_lo); scat1< 1>(vv1,  xs, g, n0, ch_lo); \
    scat1< 2>(vv2,  xs, g, n0, ch_lo); scat1< 3>(vv3,  xs, g, n0, ch_lo); \
    scat1< 4>(vv4,  xs, g, n0, ch_lo); scat1< 5>(vv5,  xs, g, n0, ch_lo); \
    scat1< 6>(vv6,  xs, g, n0, ch_lo); scat1< 7>(vv7,  xs, g, n0, ch_lo); \
    scat1< 8>(vv8,  xs, g, n0, ch_lo); scat1< 9>(vv9,  xs, g, n0, ch_lo); \
    scat1<10>(vv10, xs, g, n0, ch_lo); scat1<11>(vv11, xs, g, n0, ch_lo); \
    scat1<12>(vv12, xs, g, n0, ch_lo); scat1<13>(vv13, xs, g, n0, ch_lo); \
    scat1<14>(vv14, xs, g, n0, ch_lo); scat1<15>(vv15, xs, g, n0, ch_lo);

// ---------------------------------------------------------------------------
// v10: v9's two-tile pipeline with a spill-proof prefetch (16 named regs,
// by-value scatter). Tile-1 loads issue before mfma1(t0) and land after
// zwrite(t0); their lifetime ends before mfma2, so acc2's 64-reg peak never
// coexists with the prefetch.
// ---------------------------------------------------------------------------
template<int HW>
__device__ __forceinline__ void level3_pair(
    const float* __restrict__ x,
    const unsigned short* __restrict__ A1,
    const unsigned short* __restrict__ A2,
    const float* __restrict__ b1, const float* __restrict__ b2,
    float* __restrict__ o, int px0,        // tiles at px0, px0+64
    unsigned char* __restrict__ smem)
{
    unsigned short* xs = (unsigned short*)smem;
    unsigned short* zs = (unsigned short*)(smem + X_BYTES);
    float*          cb = (float*)(smem + X_BYTES);

    const int t = (int)threadIdx.x;
    const int lane = t & 63, w = t >> 6;
    const int q = lane >> 4, n = lane & 15;
    const short8* A1f = (const short8*)A1;
    const short8* A2f = (const short8*)A2;

    const int ch_lo = t >> 4;              // 0..15
    const int pp = t & 15;                 // px = 4*pp + e
    const int g = pp >> 2;
    const int n0 = (pp & 3) * 4;
    const float* xp = x + (size_t)ch_lo * HW + px0 + 4 * pp;

    float4v vv0, vv1, vv2, vv3, vv4, vv5, vv6, vv7;
    float4v vv8, vv9, vv10, vv11, vv12, vv13, vv14, vv15;

    // ---- prologue: tile 0 stage ----
    LDALL(0)
    SCALL()
    __syncthreads();                                   // (1) x frags visible
    short8 xf[8];
    fragread(xf, xs, w, lane);
    __syncthreads();                                   // (2) X free for refill

    // ---- tile 0 body; tile 1 prefetch in flight under mfma1 ----
    LDALL(64)
    float4v acc1[4];
    mfma1(acc1, xf, A1f, b1, lane, q);
    zwrite(acc1, zs, w, q, n);
    SCALL()                                            // waits loads here
    __syncthreads();                                   // (3) z + X(t1) visible
    float4v acc2[4][4];
    mfma2(acc2, zs, A2f, b2, lane, w, q);
    __syncthreads();                                   // (4) all z reads done
    fragread(xf, xs, w, lane);                         // t1 frags
    cstore<HW>(acc2, cb, o, px0, lane, w, q, n);
    __syncthreads();                                   // (5) C reads done

    // ---- tile 1 body ----
    mfma1(acc1, xf, A1f, b1, lane, q);
    zwrite(acc1, zs, w, q, n);
    __syncthreads();                                   // (6) z ready
    mfma2(acc2, zs, A2f, b2, lane, w, q);
    __syncthreads();                                   // (7) z reads done
    cstore<HW>(acc2, cb, o, px0 + 64, lane, w, q, n);
}

__global__ __launch_bounds__(256, 3) void fused_v10(
    const float* __restrict__ x0, const float* __restrict__ x1, const float* __restrict__ x2,
    const float* __restrict__ b1_0, const float* __restrict__ b2_0,
    const float* __restrict__ b1_1, const float* __restrict__ b2_1,
    const float* __restrict__ b1_2, const float* __restrict__ b2_2,
    const unsigned short* __restrict__ wpk, float* __restrict__ out)
{
    __shared__ __align__(16) unsigned char smem[SMEM_BYTES];
    const int bi = (int)blockIdx.x;

    if (bi < 512) {                         // level 0: 4 batches x 128 pair-tiles
        int b = bi >> 7, px0 = (bi & 127) * 128;
        level3_pair<16384>(x0 + (size_t)b * 4194304, wpk, wpk + 16384, b1_0, b2_0,
                           out + (size_t)b * 4194304, px0, smem);
    } else if (bi < 640) {                  // level 1: 4 x 32 pair-tiles
        int r = bi - 512, b = r >> 5, px0 = (r & 31) * 128;
        level3_pair<4096>(x1 + (size_t)b * 1048576, wpk + 40960, wpk + 57344,
                          b1_1, b2_1, out + 16777216 + (size_t)b * 1048576, px0, smem);
    } else {                                // level 2: 4 x 8 pair-tiles
        int r = bi - 640, b = r >> 3, px0 = (r & 7) * 128;
        level3_pair<1024>(x2 + (size_t)b * 262144, wpk + 81920, wpk + 98304,
                          b1_2, b2_2, out + 20971520 + (size_t)b * 262144, px0, smem);
    }
}

extern "C" void kernel_launch(void* const* d_in, const int* in_sizes, int n_in,
                              void* d_out, int out_size, void* d_ws, size_t ws_size,
                              hipStream_t stream) {
    const float* x0   = (const float*)d_in[0];
    const float* x1   = (const float*)d_in[1];
    const float* x2   = (const float*)d_in[2];
    const float* W1_0 = (const float*)d_in[3];
    const float* b1_0 = (const float*)d_in[4];
    const float* W2_0 = (const float*)d_in[5];
    const float* b2_0 = (const float*)d_in[6];
    const float* W1_1 = (const float*)d_in[7];
    const float* b1_1 = (const float*)d_in[8];
    const float* W2_1 = (const float*)d_in[9];
    const float* b2_1 = (const float*)d_in[10];
    const float* W1_2 = (const float*)d_in[11];
    const float* b1_2 = (const float*)d_in[12];
    const float* W2_2 = (const float*)d_in[13];
    const float* b2_2 = (const float*)d_in[14];
    float* out = (float*)d_out;
    unsigned short* wpk = (unsigned short*)d_ws;   // needs 245760 B

    prepack<<<dim3(480), dim3(256), 0, stream>>>(W1_0, W2_0, W1_1, W2_1, W1_2, W2_2, wpk);
    fused_v10<<<dim3(672), dim3(256), 0, stream>>>(
        x0, x1, x2, b1_0, b2_0, b1_1, b2_1, b1_2, b2_2, wpk, out);
}

// Round 8
// 200.027 us; speedup vs baseline: 1.1307x; 1.1307x over previous
//
#include <hip/hip_runtime.h>

typedef __attribute__((ext_vector_type(8))) short short8;
typedef __attribute__((ext_vector_type(4))) float float4v;

__device__ __forceinline__ unsigned short f2bf(float f) {
    unsigned u = __float_as_uint(f);
    u = (u + 0x7FFFu + ((u >> 16) & 1u)) >> 16;
    return (unsigned short)u;
}

#define XSET 520   // 512 data + 8 pad ushorts per (g,ks) fragment set
#define CROW 68    // 64 px + 4 pad floats per staged C row
// LDS map:
//   [0, 33312)      X frags (never aliased)
//   [33312, 50720)  Z frags (12480 B) / C staging (17408 B), barrier-separated
#define X_BYTES 33312
#define SMEM_BYTES 50720   // 3 blocks/CU (LDS-capped; VGPR bound must not add to it)

// ---------------------------------------------------------------------------
// Prepack: W1 [256x64], W2 [96x256] ([cin,cout]) -> bf16 MFMA A-frag order.
// ---------------------------------------------------------------------------
__global__ void prepack(const float* __restrict__ W1_0, const float* __restrict__ W2_0,
                        const float* __restrict__ W1_1, const float* __restrict__ W2_1,
                        const float* __restrict__ W1_2, const float* __restrict__ W2_2,
                        unsigned short* __restrict__ ws) {
    int e = blockIdx.x * 256 + threadIdx.x;
    if (e >= 3 * 40960) return;
    int l = e / 40960, r = e % 40960;
    const float* W1 = (l == 0) ? W1_0 : (l == 1) ? W1_1 : W1_2;
    const float* W2 = (l == 0) ? W2_0 : (l == 1) ? W2_1 : W2_2;
    unsigned short* base = ws + l * 40960;
    if (r < 16384) {
        int j = r & 7, lane = (r >> 3) & 63, fs = r >> 9;
        int mt = fs >> 3, ks = fs & 7;
        int k = ks * 32 + (lane >> 4) * 8 + j;
        int m = mt * 16 + (lane & 15);
        base[r] = f2bf(W1[k * 64 + m]);
    } else {
        int r2 = r - 16384;
        int j = r2 & 7, lane = (r2 >> 3) & 63, fs = r2 >> 9;
        int mt = fs / 3, ks = fs - mt * 3;
        int k = ks * 32 + (lane >> 4) * 8 + j;
        int m = mt * 16 + (lane & 15);
        base[16384 + r2] = f2bf(W2[k * 256 + m]);
    }
}

// ---- helpers ---------------------------------------------------------------

template<int I>
__device__ __forceinline__ void scat1(float4v vv, unsigned short* xs,
                                      int g, int n0, int ch_lo) {
    const int ch = I * 16 + ch_lo;
    const int ks = ch >> 5, qq = (ch >> 3) & 3, j = ch & 7;
    // +g*8 ushort (16 B) skew breaks the mod-32-bank degeneracy.
    unsigned short* base = xs + (g * 8 + ks) * XSET + g * 8 + j;
    base[(qq * 16 + n0 + 0) * 8] = f2bf(vv[0]);
    base[(qq * 16 + n0 + 1) * 8] = f2bf(vv[1]);
    base[(qq * 16 + n0 + 2) * 8] = f2bf(vv[2]);
    base[(qq * 16 + n0 + 3) * 8] = f2bf(vv[3]);
}

__device__ __forceinline__ void fragread(short8 xf[8], const unsigned short* xs,
                                         int w, int lane) {
#pragma unroll
    for (int ks = 0; ks < 8; ++ks)
        xf[ks] = *(const short8*)(xs + (w * 8 + ks) * XSET + w * 8 + lane * 8);
}

__device__ __forceinline__ void mfma1(float4v acc1[4], const short8 xf[8],
                                      const short8* __restrict__ A1f,
                                      const float* __restrict__ b1, int lane, int q) {
#pragma unroll
    for (int mt = 0; mt < 4; ++mt)
        acc1[mt] = *(const float4v*)(b1 + mt * 16 + q * 4);
#pragma unroll
    for (int ks = 0; ks < 8; ++ks)
#pragma unroll
        for (int mt = 0; mt < 4; ++mt)
            acc1[mt] = __builtin_amdgcn_mfma_f32_16x16x32_bf16(
                A1f[(mt * 8 + ks) * 64 + lane], xf[ks], acc1[mt], 0, 0, 0);
}

__device__ __forceinline__ void zwrite(const float4v acc1[4], unsigned short* zs,
                                       int w, int q, int n) {
    unsigned short* zg = zs + w * 3 * XSET;
#pragma unroll
    for (int mt = 0; mt < 4; ++mt) {
        const int kb = mt * 16 + q * 4;
        unsigned long long pk =
              (unsigned long long)f2bf(acc1[mt][0])
            | ((unsigned long long)f2bf(acc1[mt][1]) << 16)
            | ((unsigned long long)f2bf(acc1[mt][2]) << 32)
            | ((unsigned long long)f2bf(acc1[mt][3]) << 48);
        *(unsigned long long*)(zg + (kb >> 5) * XSET +
            (((kb >> 3) & 3) * 16 + n) * 8 + (kb & 7)) = pk;
        if (mt >= 2) {
            const int kr = kb + 32;        // relu copy at k = 64 + (ch-32)
            unsigned long long pr =
                  (unsigned long long)f2bf(fmaxf(acc1[mt][0], 0.f))
                | ((unsigned long long)f2bf(fmaxf(acc1[mt][1], 0.f)) << 16)
                | ((unsigned long long)f2bf(fmaxf(acc1[mt][2], 0.f)) << 32)
                | ((unsigned long long)f2bf(fmaxf(acc1[mt][3], 0.f)) << 48);
            *(unsigned long long*)(zg + (kr >> 5) * XSET +
                (((kr >> 3) & 3) * 16 + n) * 8 + (kr & 7)) = pr;
        }
    }
}

__device__ __forceinline__ void mfma2(float4v acc2[4][4], const unsigned short* zs,
                                      const short8* __restrict__ A2f,
                                      const float* __restrict__ b2,
                                      int lane, int w, int q) {
#pragma unroll
    for (int mm = 0; mm < 4; ++mm) {
        float4v bb = *(const float4v*)(b2 + (w * 4 + mm) * 16 + q * 4);
#pragma unroll
        for (int g = 0; g < 4; ++g) acc2[mm][g] = bb;
    }
#pragma unroll
    for (int g = 0; g < 4; ++g) {
        short8 zf[3];
#pragma unroll
        for (int ks = 0; ks < 3; ++ks)
            zf[ks] = *(const short8*)(zs + (g * 3 + ks) * XSET + lane * 8);
#pragma unroll
        for (int ks = 0; ks < 3; ++ks)
#pragma unroll
            for (int mm = 0; mm < 4; ++mm)
                acc2[mm][g] = __builtin_amdgcn_mfma_f32_16x16x32_bf16(
                    A2f[((w * 4 + mm) * 3 + ks) * 64 + lane], zf[ks], acc2[mm][g], 0, 0, 0);
    }
}

// C staging: 16-row wave-private slots, 4 passes (one mm each). DS ops of one
// wave execute in order -> no barrier inside.
template<int HW>
__device__ __forceinline__ void cstore(const float4v acc2[4][4], float* cb,
                                       float* __restrict__ o, int px0,
                                       int lane, int w, int q, int n) {
    float* cww = cb + w * 16 * CROW;
    const int chs = lane >> 4, ppx = lane & 15;
#pragma unroll
    for (int mm = 0; mm < 4; ++mm) {
#pragma unroll
        for (int g = 0; g < 4; ++g)
#pragma unroll
            for (int r = 0; r < 4; ++r)
                cww[(q * 4 + r) * CROW + g * 16 + n] = acc2[mm][g][r];
        float* op = o + (size_t)(w * 64 + mm * 16 + chs) * HW + px0 + 4 * ppx;
#pragma unroll
        for (int i = 0; i < 4; ++i) {
            float4v vv = *(const float4v*)(cww + (i * 4 + chs) * CROW + 4 * ppx);
            *(float4v*)(op + (size_t)(i * 4) * HW) = vv;
        }
    }
}

#define LDALL(OFF)                                                        \
    vv0  = *(const float4v*)(xp + (OFF) + (size_t)( 0 * 16) * HW);        \
    vv1  = *(const float4v*)(xp + (OFF) + (size_t)( 1 * 16) * HW);        \
    vv2  = *(const float4v*)(xp + (OFF) + (size_t)( 2 * 16) * HW);        \
    vv3  = *(const float4v*)(xp + (OFF) + (size_t)( 3 * 16) * HW);        \
    vv4  = *(const float4v*)(xp + (OFF) + (size_t)( 4 * 16) * HW);        \
    vv5  = *(const float4v*)(xp + (OFF) + (size_t)( 5 * 16) * HW);        \
    vv6  = *(const float4v*)(xp + (OFF) + (size_t)( 6 * 16) * HW);        \
    vv7  = *(const float4v*)(xp + (OFF) + (size_t)( 7 * 16) * HW);        \
    vv8  = *(const float4v*)(xp + (OFF) + (size_t)( 8 * 16) * HW);        \
    vv9  = *(const float4v*)(xp + (OFF) + (size_t)( 9 * 16) * HW);        \
    vv10 = *(const float4v*)(xp + (OFF) + (size_t)(10 * 16) * HW);        \
    vv11 = *(const float4v*)(xp + (OFF) + (size_t)(11 * 16) * HW);        \
    vv12 = *(const float4v*)(xp + (OFF) + (size_t)(12 * 16) * HW);        \
    vv13 = *(const float4v*)(xp + (OFF) + (size_t)(13 * 16) * HW);        \
    vv14 = *(const float4v*)(xp + (OFF) + (size_t)(14 * 16) * HW);        \
    vv15 = *(const float4v*)(xp + (OFF) + (size_t)(15 * 16) * HW);

#define SCALL()                                                           \
    scat1< 0>(vv0,  xs, g, n0, ch_lo); scat1< 1>(vv1,  xs, g, n0, ch_lo); \
    scat1< 2>(vv2,  xs, g, n0, ch_lo); scat1< 3>(vv3,  xs, g, n0, ch_lo); \
    scat1< 4>(vv4,  xs, g, n0, ch_lo); scat1< 5>(vv5,  xs, g, n0, ch_lo); \
    scat1< 6>(vv6,  xs, g, n0, ch_lo); scat1< 7>(vv7,  xs, g, n0, ch_lo); \
    scat1< 8>(vv8,  xs, g, n0, ch_lo); scat1< 9>(vv9,  xs, g, n0, ch_lo); \
    scat1<10>(vv10, xs, g, n0, ch_lo); scat1<11>(vv11, xs, g, n0, ch_lo); \
    scat1<12>(vv12, xs, g, n0, ch_lo); scat1<13>(vv13, xs, g, n0, ch_lo); \
    scat1<14>(vv14, xs, g, n0, ch_lo); scat1<15>(vv15, xs, g, n0, ch_lo);

// ---------------------------------------------------------------------------
// v11 == v10 except __launch_bounds__(256, 2): the v8/v9/v10 spill (VGPR
// pinned at 84 = 512/6, FETCH/WRITE inflated by scratch) is the allocator
// forcing a 6-wave/SIMD occupancy tier, not true pressure (peak ~140 < 170).
// Occupancy is LDS-capped at 3 blocks/CU either way, so relaxing the VGPR
// floor to 2 waves/EU costs nothing and removes the spill motive (v7
// precedent: bounds(256,2) -> allocator freely used 112 VGPR).
// ---------------------------------------------------------------------------
template<int HW>
__device__ __forceinline__ void level3_pair(
    const float* __restrict__ x,
    const unsigned short* __restrict__ A1,
    const unsigned short* __restrict__ A2,
    const float* __restrict__ b1, const float* __restrict__ b2,
    float* __restrict__ o, int px0,        // tiles at px0, px0+64
    unsigned char* __restrict__ smem)
{
    unsigned short* xs = (unsigned short*)smem;
    unsigned short* zs = (unsigned short*)(smem + X_BYTES);
    float*          cb = (float*)(smem + X_BYTES);

    const int t = (int)threadIdx.x;
    const int lane = t & 63, w = t >> 6;
    const int q = lane >> 4, n = lane & 15;
    const short8* A1f = (const short8*)A1;
    const short8* A2f = (const short8*)A2;

    const int ch_lo = t >> 4;              // 0..15
    const int pp = t & 15;                 // px = 4*pp + e
    const int g = pp >> 2;
    const int n0 = (pp & 3) * 4;
    const float* xp = x + (size_t)ch_lo * HW + px0 + 4 * pp;

    float4v vv0, vv1, vv2, vv3, vv4, vv5, vv6, vv7;
    float4v vv8, vv9, vv10, vv11, vv12, vv13, vv14, vv15;

    // ---- prologue: tile 0 stage ----
    LDALL(0)
    SCALL()
    __syncthreads();                                   // (1) x frags visible
    short8 xf[8];
    fragread(xf, xs, w, lane);
    __syncthreads();                                   // (2) X free for refill

    // ---- tile 0 body; tile 1 prefetch in flight under mfma1 ----
    LDALL(64)
    float4v acc1[4];
    mfma1(acc1, xf, A1f, b1, lane, q);
    zwrite(acc1, zs, w, q, n);
    SCALL()                                            // waits loads here
    __syncthreads();                                   // (3) z + X(t1) visible
    float4v acc2[4][4];
    mfma2(acc2, zs, A2f, b2, lane, w, q);
    __syncthreads();                                   // (4) all z reads done
    fragread(xf, xs, w, lane);                         // t1 frags
    cstore<HW>(acc2, cb, o, px0, lane, w, q, n);
    __syncthreads();                                   // (5) C reads done

    // ---- tile 1 body ----
    mfma1(acc1, xf, A1f, b1, lane, q);
    zwrite(acc1, zs, w, q, n);
    __syncthreads();                                   // (6) z ready
    mfma2(acc2, zs, A2f, b2, lane, w, q);
    __syncthreads();                                   // (7) z reads done
    cstore<HW>(acc2, cb, o, px0 + 64, lane, w, q, n);
}

__global__ __launch_bounds__(256, 2) void fused_v11(
    const float* __restrict__ x0, const float* __restrict__ x1, const float* __restrict__ x2,
    const float* __restrict__ b1_0, const float* __restrict__ b2_0,
    const float* __restrict__ b1_1, const float* __restrict__ b2_1,
    const float* __restrict__ b1_2, const float* __restrict__ b2_2,
    const unsigned short* __restrict__ wpk, float* __restrict__ out)
{
    __shared__ __align__(16) unsigned char smem[SMEM_BYTES];
    const int bi = (int)blockIdx.x;

    if (bi < 512) {                         // level 0: 4 batches x 128 pair-tiles
        int b = bi >> 7, px0 = (bi & 127) * 128;
        level3_pair<16384>(x0 + (size_t)b * 4194304, wpk, wpk + 16384, b1_0, b2_0,
                           out + (size_t)b * 4194304, px0, smem);
    } else if (bi < 640) {                  // level 1: 4 x 32 pair-tiles
        int r = bi - 512, b = r >> 5, px0 = (r & 31) * 128;
        level3_pair<4096>(x1 + (size_t)b * 1048576, wpk + 40960, wpk + 57344,
                          b1_1, b2_1, out + 16777216 + (size_t)b * 1048576, px0, smem);
    } else {                                // level 2: 4 x 8 pair-tiles
        int r = bi - 640, b = r >> 3, px0 = (r & 7) * 128;
        level3_pair<1024>(x2 + (size_t)b * 262144, wpk + 81920, wpk + 98304,
                          b1_2, b2_2, out + 20971520 + (size_t)b * 262144, px0, smem);
    }
}

extern "C" void kernel_launch(void* const* d_in, const int* in_sizes, int n_in,
                              void* d_out, int out_size, void* d_ws, size_t ws_size,
                              hipStream_t stream) {
    const float* x0   = (const float*)d_in[0];
    const float* x1   = (const float*)d_in[1];
    const float* x2   = (const float*)d_in[2];
    const float* W1_0 = (const float*)d_in[3];
    const float* b1_0 = (const float*)d_in[4];
    const float* W2_0 = (const float*)d_in[5];
    const float* b2_0 = (const float*)d_in[6];
    const float* W1_1 = (const float*)d_in[7];
    const float* b1_1 = (const float*)d_in[8];
    const float* W2_1 = (const float*)d_in[9];
    const float* b2_1 = (const float*)d_in[10];
    const float* W1_2 = (const float*)d_in[11];
    const float* b1_2 = (const float*)d_in[12];
    const float* W2_2 = (const float*)d_in[13];
    const float* b2_2 = (const float*)d_in[14];
    float* out = (float*)d_out;
    unsigned short* wpk = (unsigned short*)d_ws;   // needs 245760 B

    prepack<<<dim3(480), dim3(256), 0, stream>>>(W1_0, W2_0, W1_1, W2_1, W1_2, W2_2, wpk);
    fused_v11<<<dim3(672), dim3(256), 0, stream>>>(
        x0, x1, x2, b1_0, b2_0, b1_1, b2_1, b1_2, b2_2, wpk, out);
}